// Round 1
// baseline (503.682 us; speedup 1.0000x reference)
//
#include <hip/hip_runtime.h>
#include <math.h>

#define B_    2
#define H_    64
#define W_    64
#define L_    4096            // H*W
#define DM    96              // d_model
#define DI    192             // d_inner
#define NST   16              // d_state
#define DTR   6               // dt_rank
#define KD    4               // directions
#define CHUNK 64
#define NCH   64              // L / CHUNK
#define NCOEF 38              // DTR + 2*NST

__device__ __forceinline__ float softplusf(float x){
    return fmaxf(x, 0.f) + __logf(1.f + __expf(-fabsf(x)));
}
__device__ __forceinline__ float siluf(float x){
    return x / (1.f + __expf(-x));
}

// ---------------- K1: in_proj GEMM (B*L x 384 = x @ W^T), split into xin(NCHW) and z(NLC)
__global__ __launch_bounds__(256) void k_inproj(const float* __restrict__ x,
        const float* __restrict__ w, float* __restrict__ xin, float* __restrict__ z){
    __shared__ float xs[64][DM + 1];
    int tile = blockIdx.x;                 // B*L/64 = 128
    int b = tile >> 6;
    int posbase = (tile & 63) * 64;
    const float* xrow = x + ((size_t)b * L_ + posbase) * DM;
    for (int i = threadIdx.x; i < 64 * DM; i += 256){
        xs[i / DM][i % DM] = xrow[i];
    }
    __syncthreads();
    // first half -> xin[b][o][pos]  (channel-major for conv)
    for (int i = threadIdx.x; i < 64 * DI; i += 256){
        int p = i & 63, o = i >> 6;
        const float* wr = w + o * DM;
        float acc = 0.f;
        #pragma unroll 8
        for (int c = 0; c < DM; ++c) acc = fmaf(xs[p][c], wr[c], acc);
        xin[((size_t)b * DI + o) * L_ + posbase + p] = acc;
    }
    // second half -> z[b][pos][o]
    for (int i = threadIdx.x; i < 64 * DI; i += 256){
        int o = i % DI, p = i / DI;
        const float* wr = w + (DI + o) * DM;
        float acc = 0.f;
        #pragma unroll 8
        for (int c = 0; c < DM; ++c) acc = fmaf(xs[p][c], wr[c], acc);
        z[((size_t)b * L_ + posbase + p) * DI + o] = acc;
    }
}

// ---------------- K2: depthwise 3x3 conv + bias + SiLU; writes xc (hw) and xcT (wh)
__global__ __launch_bounds__(256) void k_conv(const float* __restrict__ xin,
        const float* __restrict__ cw, const float* __restrict__ cb,
        float* __restrict__ xc, float* __restrict__ xcT){
    int id = blockIdx.x;                   // B*DI*4
    int t = id & 3; int c = (id >> 2) % DI; int b = id / (4 * DI);
    int h0 = (t >> 1) * 32, w0 = (t & 1) * 32;
    __shared__ float in_s[34][36];
    __shared__ float out_s[32][33];
    const float* src = xin + ((size_t)b * DI + c) * L_;
    for (int i = threadIdx.x; i < 34 * 34; i += 256){
        int r = i / 34, q = i % 34;
        int hh = h0 + r - 1, ww = w0 + q - 1;
        float v = 0.f;
        if (hh >= 0 && hh < H_ && ww >= 0 && ww < W_) v = src[hh * W_ + ww];
        in_s[r][q] = v;
    }
    __syncthreads();
    float w9[9];
    #pragma unroll
    for (int j = 0; j < 9; ++j) w9[j] = cw[c * 9 + j];
    float bias = cb[c];
    for (int i = threadIdx.x; i < 32 * 32; i += 256){
        int r = i >> 5, q = i & 31;
        float acc = bias;
        #pragma unroll
        for (int dy = 0; dy < 3; ++dy)
            #pragma unroll
            for (int dx = 0; dx < 3; ++dx)
                acc = fmaf(w9[dy * 3 + dx], in_s[r + dy][q + dx], acc);
        acc = siluf(acc);
        out_s[r][q] = acc;
        xc[((size_t)b * DI + c) * L_ + (h0 + r) * W_ + (w0 + q)] = acc;
    }
    __syncthreads();
    for (int i = threadIdx.x; i < 32 * 32; i += 256){
        int r = i >> 5, q = i & 31;  // r = local w, q = local h
        xcT[((size_t)b * DI + c) * L_ + (w0 + r) * H_ + (h0 + q)] = out_s[q][r];
    }
}

// ---------------- K3: x_dbl[b,k,j,l] = sum_c xs[b,k,c,l] * x_proj_w[k,c,j]
__global__ __launch_bounds__(256) void k_xdbl(const float* __restrict__ xc,
        const float* __restrict__ xcT, const float* __restrict__ xpw,
        float* __restrict__ xdbl){
    int id = blockIdx.x;                   // B*K*(L/256) = 128
    int lt = id & 15; int k = (id >> 4) & 3; int b = id >> 6;
    int lbase = lt * 256;
    __shared__ float ws[DI][NCOEF];
    for (int i = threadIdx.x; i < DI * NCOEF; i += 256)
        ws[i / NCOEF][i % NCOEF] = xpw[k * DI * NCOEF + i];
    __syncthreads();
    const float* src = ((k & 1) ? xcT : xc) + (size_t)b * DI * L_;
    bool rev = (k >= 2);
    int l = lbase + threadIdx.x;
    int lk = rev ? (L_ - 1 - l) : l;
    float acc[NCOEF];
    #pragma unroll
    for (int j = 0; j < NCOEF; ++j) acc[j] = 0.f;
    for (int c = 0; c < DI; ++c){
        float v = src[(size_t)c * L_ + lk];
        #pragma unroll
        for (int j = 0; j < NCOEF; ++j) acc[j] = fmaf(v, ws[c][j], acc[j]);
    }
    float* dst = xdbl + (size_t)(b * KD + k) * NCOEF * L_ + l;
    #pragma unroll
    for (int j = 0; j < NCOEF; ++j) dst[(size_t)j * L_] = acc[j];
}

// ---------------- K4: scan phase 1 — per-chunk summaries P (prod dA) and Q
__global__ __launch_bounds__(192) void k_scan1(const float* __restrict__ xc,
        const float* __restrict__ xcT, const float* __restrict__ xdbl,
        const float* __restrict__ dtw, const float* __restrict__ dtb,
        const float* __restrict__ Alog,
        float* __restrict__ Pbuf, float* __restrict__ Qbuf){
    int id = blockIdx.x;                   // B*K*NCH = 512
    int ch = id & 63; int k = (id >> 6) & 3; int b = id >> 8;
    int lbase = ch * CHUNK;
    __shared__ float u_s[DI][CHUNK + 1];
    __shared__ float co_s[DTR + NST][CHUNK];
    const float* src = ((k & 1) ? xcT : xc) + (size_t)b * DI * L_;
    bool rev = (k >= 2);
    for (int i = threadIdx.x; i < DI * CHUNK; i += 192){
        int r = i >> 6, q = i & 63;
        int lk = rev ? (L_ - 1 - (lbase + q)) : (lbase + q);
        u_s[r][q] = src[(size_t)r * L_ + lk];
    }
    const float* xd = xdbl + (size_t)(b * KD + k) * NCOEF * L_ + lbase;
    for (int i = threadIdx.x; i < (DTR + NST) * CHUNK; i += 192){
        int r = i >> 6, q = i & 63;
        co_s[r][q] = xd[(size_t)r * L_ + q];
    }
    __syncthreads();
    int d = threadIdx.x;
    int kd = k * DI + d;
    float wdt[DTR];
    #pragma unroll
    for (int r = 0; r < DTR; ++r) wdt[r] = dtw[kd * DTR + r];
    float bias = dtb[kd];
    float A[NST];
    #pragma unroll
    for (int n = 0; n < NST; ++n) A[n] = -__expf(Alog[kd * NST + n]);
    float P[NST], Q[NST];
    #pragma unroll
    for (int n = 0; n < NST; ++n){ P[n] = 1.f; Q[n] = 0.f; }
    for (int i = 0; i < CHUNK; ++i){
        float draw = bias;
        #pragma unroll
        for (int r = 0; r < DTR; ++r) draw = fmaf(wdt[r], co_s[r][i], draw);
        float delta = softplusf(draw);
        float du = delta * u_s[d][i];
        #pragma unroll
        for (int n = 0; n < NST; ++n){
            float dA = __expf(delta * A[n]);
            P[n] *= dA;
            Q[n] = fmaf(dA, Q[n], du * co_s[DTR + n][i]);
        }
    }
    size_t base = ((size_t)((b * KD + k) * NCH + ch) * NST) * DI + d;
    #pragma unroll
    for (int n = 0; n < NST; ++n){
        Pbuf[base + (size_t)n * DI] = P[n];
        Qbuf[base + (size_t)n * DI] = Q[n];
    }
}

// ---------------- K5: scan phase 2 — inter-chunk scan; Qbuf becomes x_start per chunk
__global__ __launch_bounds__(256) void k_scan2(const float* __restrict__ Pbuf,
        float* __restrict__ Qbuf){
    int t = blockIdx.x * 256 + threadIdx.x;   // B*K*NST*DI = 24576
    if (t >= B_ * KD * NST * DI) return;
    int d = t % DI; int n = (t / DI) % NST; int bk = t / (DI * NST);
    size_t stride = (size_t)NST * DI;
    size_t idx = (size_t)bk * NCH * stride + (size_t)n * DI + d;
    float x = 0.f;
    for (int c = 0; c < NCH; ++c){
        float p = Pbuf[idx];
        float q = Qbuf[idx];
        Qbuf[idx] = x;                 // x_start for this chunk
        x = fmaf(p, x, q);
        idx += stride;
    }
}

// ---------------- K6: scan phase 3 — replay with x_start, emit y into yhw / ywh
__global__ __launch_bounds__(192) void k_scan3(const float* __restrict__ xc,
        const float* __restrict__ xcT, const float* __restrict__ xdbl,
        const float* __restrict__ dtw, const float* __restrict__ dtb,
        const float* __restrict__ Alog, const float* __restrict__ Dskip,
        const float* __restrict__ Qbuf,
        float* __restrict__ yhw, float* __restrict__ ywh){
    int id = blockIdx.x;                   // 512
    int ch = id & 63; int k = (id >> 6) & 3; int b = id >> 8;
    int lbase = ch * CHUNK;
    __shared__ float u_s[DI][CHUNK + 1];
    __shared__ float co_s[NCOEF][CHUNK];
    __shared__ float y_s[DI][17];
    const float* src = ((k & 1) ? xcT : xc) + (size_t)b * DI * L_;
    bool rev = (k >= 2);
    for (int i = threadIdx.x; i < DI * CHUNK; i += 192){
        int r = i >> 6, q = i & 63;
        int lk = rev ? (L_ - 1 - (lbase + q)) : (lbase + q);
        u_s[r][q] = src[(size_t)r * L_ + lk];
    }
    const float* xd = xdbl + (size_t)(b * KD + k) * NCOEF * L_ + lbase;
    for (int i = threadIdx.x; i < NCOEF * CHUNK; i += 192){
        int r = i >> 6, q = i & 63;
        co_s[r][q] = xd[(size_t)r * L_ + q];
    }
    __syncthreads();
    int d = threadIdx.x;
    int kd = k * DI + d;
    float wdt[DTR];
    #pragma unroll
    for (int r = 0; r < DTR; ++r) wdt[r] = dtw[kd * DTR + r];
    float bias = dtb[kd];
    float A[NST];
    #pragma unroll
    for (int n = 0; n < NST; ++n) A[n] = -__expf(Alog[kd * NST + n]);
    float Dval = Dskip[kd];
    size_t base = ((size_t)((b * KD + k) * NCH + ch) * NST) * DI + d;
    float xst[NST];
    #pragma unroll
    for (int n = 0; n < NST; ++n) xst[n] = Qbuf[base + (size_t)n * DI];
    float* dst = ((k & 1) ? ywh : yhw) + (size_t)b * DI * L_;
    for (int blk = 0; blk < 4; ++blk){
        for (int ii = 0; ii < 16; ++ii){
            int i = blk * 16 + ii;
            float draw = bias;
            #pragma unroll
            for (int r = 0; r < DTR; ++r) draw = fmaf(wdt[r], co_s[r][i], draw);
            float delta = softplusf(draw);
            float du = delta * u_s[d][i];
            float y = 0.f;
            #pragma unroll
            for (int n = 0; n < NST; ++n){
                float dA = __expf(delta * A[n]);
                xst[n] = fmaf(dA, xst[n], du * co_s[DTR + n][i]);
                y = fmaf(xst[n], co_s[DTR + NST + n][i], y);
            }
            y = fmaf(u_s[d][i], Dval, y);
            y_s[d][ii] = y;
        }
        __syncthreads();
        for (int j = threadIdx.x; j < DI * 16; j += 192){
            int r = j >> 4, q = j & 15;
            int i = blk * 16 + q;
            int lk = rev ? (L_ - 1 - (lbase + i)) : (lbase + i);
            unsafeAtomicAdd(&dst[(size_t)r * L_ + lk], y_s[r][q]);
        }
        __syncthreads();
    }
}

// ---------------- K6b: yhw[h,w] += transpose(ywh)[h,w]
__global__ __launch_bounds__(256) void k_whadd(const float* __restrict__ ywh,
        float* __restrict__ yhw){
    int id = blockIdx.x;                   // B*DI*4
    int t = id & 3; int c = (id >> 2) % DI; int b = id / (4 * DI);
    int wb = (t >> 1) * 32, hb = (t & 1) * 32;
    __shared__ float ts[32][33];
    const float* src = ywh + ((size_t)b * DI + c) * L_;
    float* dst = yhw + ((size_t)b * DI + c) * L_;
    for (int i = threadIdx.x; i < 1024; i += 256){
        int r = i >> 5, q = i & 31;        // r: w, q: h
        ts[r][q] = src[(wb + r) * H_ + hb + q];
    }
    __syncthreads();
    for (int i = threadIdx.x; i < 1024; i += 256){
        int r = i >> 5, q = i & 31;        // r: h, q: w
        dst[(hb + r) * W_ + wb + q] += ts[q][r];
    }
}

// ---------------- K7: LayerNorm over channel + SiLU(z) gate -> yg[b,pos,d]
__global__ __launch_bounds__(256) void k_ln(const float* __restrict__ yhw,
        const float* __restrict__ z, const float* __restrict__ lnw,
        const float* __restrict__ lnb, float* __restrict__ yg){
    int id = blockIdx.x;                   // B*L/64 = 128
    int b = id >> 6; int posbase = (id & 63) * 64;
    __shared__ float ys[DI][65];
    __shared__ float rsum[4][64], rsq[4][64];
    __shared__ float mu_s[64], rs_s[64];
    const float* src = yhw + (size_t)b * DI * L_ + posbase;
    for (int i = threadIdx.x; i < DI * 64; i += 256){
        int r = i >> 6, q = i & 63;
        ys[r][q] = src[(size_t)r * L_ + q];
    }
    __syncthreads();
    int lane = threadIdx.x & 63; int part = threadIdx.x >> 6;
    float s = 0.f, sq = 0.f;
    for (int r = part * 48; r < part * 48 + 48; ++r){
        float v = ys[r][lane];
        s += v; sq = fmaf(v, v, sq);
    }
    rsum[part][lane] = s; rsq[part][lane] = sq;
    __syncthreads();
    if (part == 0){
        float S  = rsum[0][lane] + rsum[1][lane] + rsum[2][lane] + rsum[3][lane];
        float SQ = rsq[0][lane]  + rsq[1][lane]  + rsq[2][lane]  + rsq[3][lane];
        float mu = S * (1.f / DI);
        float var = SQ * (1.f / DI) - mu * mu;
        mu_s[lane] = mu;
        rs_s[lane] = rsqrtf(var + 1e-5f);
    }
    __syncthreads();
    for (int i = threadIdx.x; i < DI * 64; i += 256){
        int d = i % DI, p = i / DI;
        float v = (ys[d][p] - mu_s[p]) * rs_s[p] * lnw[d] + lnb[d];
        float zv = z[((size_t)b * L_ + posbase + p) * DI + d];
        yg[((size_t)b * L_ + posbase + p) * DI + d] = v * siluf(zv);
    }
}

// ---------------- K8: out_proj GEMM (B*L x 96 = yg @ W^T)
__global__ __launch_bounds__(256) void k_outproj(const float* __restrict__ yg,
        const float* __restrict__ w, float* __restrict__ out){
    int id = blockIdx.x;                   // 128
    int b = id >> 6; int posbase = (id & 63) * 64;
    __shared__ float ys[64][DI + 1];
    const float* src = yg + ((size_t)b * L_ + posbase) * DI;
    for (int i = threadIdx.x; i < 64 * DI; i += 256){
        ys[i / DI][i % DI] = src[i];
    }
    __syncthreads();
    for (int i = threadIdx.x; i < 64 * DM; i += 256){
        int o = i % DM, p = i / DM;
        const float* wr = w + o * DI;
        float acc = 0.f;
        #pragma unroll 8
        for (int c = 0; c < DI; ++c) acc = fmaf(ys[p][c], wr[c], acc);
        out[((size_t)b * L_ + posbase + p) * DM + o] = acc;
    }
}

extern "C" void kernel_launch(void* const* d_in, const int* in_sizes, int n_in,
                              void* d_out, int out_size, void* d_ws, size_t ws_size,
                              hipStream_t stream) {
    const float* x    = (const float*)d_in[0];
    const float* ipw  = (const float*)d_in[1];
    const float* cw   = (const float*)d_in[2];
    const float* cb   = (const float*)d_in[3];
    const float* xpw  = (const float*)d_in[4];
    const float* dtw  = (const float*)d_in[5];
    const float* dtb  = (const float*)d_in[6];
    const float* Alog = (const float*)d_in[7];
    const float* Dsk  = (const float*)d_in[8];
    const float* lnw  = (const float*)d_in[9];
    const float* lnb  = (const float*)d_in[10];
    const float* opw  = (const float*)d_in[11];
    float* out = (float*)d_out;

    float* ws = (float*)d_ws;
    const size_t SZ = (size_t)B_ * DI * L_;   // 1,572,864 floats
    float* xin  = ws;
    float* xc   = ws + 1 * SZ;
    float* xcT  = ws + 2 * SZ;
    float* z    = ws + 3 * SZ;
    float* xdbl = ws + 4 * SZ;                // B*K*38*L < SZ
    float* P    = ws + 5 * SZ;
    float* Q    = ws + 6 * SZ;
    float* yhw  = ws + 7 * SZ;
    float* ywh  = ws + 8 * SZ;
    float* yg   = xin;                        // xin dead after conv

    k_inproj<<<B_ * (L_ / 64), 256, 0, stream>>>(x, ipw, xin, z);
    k_conv<<<B_ * DI * 4, 256, 0, stream>>>(xin, cw, cb, xc, xcT);
    hipMemsetAsync(yhw, 0, 2 * SZ * sizeof(float), stream);   // yhw + ywh
    k_xdbl<<<B_ * KD * (L_ / 256), 256, 0, stream>>>(xc, xcT, xpw, xdbl);
    k_scan1<<<B_ * KD * NCH, 192, 0, stream>>>(xc, xcT, xdbl, dtw, dtb, Alog, P, Q);
    k_scan2<<<(B_ * KD * NST * DI + 255) / 256, 256, 0, stream>>>(P, Q);
    k_scan3<<<B_ * KD * NCH, 192, 0, stream>>>(xc, xcT, xdbl, dtw, dtb, Alog, Dsk, Q, yhw, ywh);
    k_whadd<<<B_ * DI * 4, 256, 0, stream>>>(ywh, yhw);
    k_ln<<<B_ * (L_ / 64), 256, 0, stream>>>(yhw, z, lnw, lnb, yg);
    k_outproj<<<B_ * (L_ / 64), 256, 0, stream>>>(yg, opw, out);
}

// Round 2
// 178.371 us; speedup vs baseline: 2.8238x; 2.8238x over previous
//
#include <hip/hip_runtime.h>
#include <math.h>

#define B_    2
#define H_    64
#define W_    64
#define L_    4096            // H*W
#define DM    96              // d_model
#define DI    192             // d_inner
#define NST   16              // d_state
#define DTR   6               // dt_rank
#define KD    4               // directions
#define CHUNK 32
#define NCH   128             // L / CHUNK
#define NCOEF 38              // DTR + 2*NST

__device__ __forceinline__ float softplusf(float x){
    return fmaxf(x, 0.f) + __logf(1.f + __expf(-fabsf(x)));
}
__device__ __forceinline__ float siluf(float x){
    return x / (1.f + __expf(-x));
}

// ---------------- K1: in_proj GEMM. C[8192][384] = x[8192][96] @ W^T.
// Tiles: M=64 pos, N=64 out. grid = 128 mtiles * 6 ntiles. nt<3 -> xin[b][o][l], nt>=3 -> z[b][l][o]
__global__ __launch_bounds__(256) void k_inproj(const float* __restrict__ x,
        const float* __restrict__ w, float* __restrict__ xin, float* __restrict__ z){
    __shared__ float As[64][DM + 1];
    __shared__ float Ws[64][DM + 1];
    int mt = blockIdx.x & 127;
    int nt = blockIdx.x >> 7;              // 0..5
    int b = mt >> 6;
    int posbase = (mt & 63) * 64;
    const float* xsrc = x + ((size_t)b * L_ + posbase) * DM;   // 6144 contiguous
    const float* wsrc = w + (size_t)nt * 64 * DM;              // 6144 contiguous
    for (int i4 = threadIdx.x; i4 < 1536; i4 += 256){
        int i = i4 * 4;
        float4 va = *(const float4*)(xsrc + i);
        float4 vw = *(const float4*)(wsrc + i);
        int r = i / DM, c = i % DM;        // DM%4==0: no row crossing
        As[r][c] = va.x; As[r][c+1] = va.y; As[r][c+2] = va.z; As[r][c+3] = va.w;
        Ws[r][c] = vw.x; Ws[r][c+1] = vw.y; Ws[r][c+2] = vw.z; Ws[r][c+3] = vw.w;
    }
    __syncthreads();
    int tx = threadIdx.x & 15;             // position group
    int ty = threadIdx.x >> 4;             // output group
    float acc[4][4];
    #pragma unroll
    for (int i = 0; i < 4; ++i)
        #pragma unroll
        for (int j = 0; j < 4; ++j) acc[i][j] = 0.f;
    #pragma unroll 4
    for (int k = 0; k < DM; ++k){
        float a0 = As[tx*4+0][k], a1 = As[tx*4+1][k], a2 = As[tx*4+2][k], a3 = As[tx*4+3][k];
        float w0 = Ws[ty*4+0][k], w1 = Ws[ty*4+1][k], w2 = Ws[ty*4+2][k], w3 = Ws[ty*4+3][k];
        acc[0][0] = fmaf(a0,w0,acc[0][0]); acc[0][1] = fmaf(a0,w1,acc[0][1]);
        acc[0][2] = fmaf(a0,w2,acc[0][2]); acc[0][3] = fmaf(a0,w3,acc[0][3]);
        acc[1][0] = fmaf(a1,w0,acc[1][0]); acc[1][1] = fmaf(a1,w1,acc[1][1]);
        acc[1][2] = fmaf(a1,w2,acc[1][2]); acc[1][3] = fmaf(a1,w3,acc[1][3]);
        acc[2][0] = fmaf(a2,w0,acc[2][0]); acc[2][1] = fmaf(a2,w1,acc[2][1]);
        acc[2][2] = fmaf(a2,w2,acc[2][2]); acc[2][3] = fmaf(a2,w3,acc[2][3]);
        acc[3][0] = fmaf(a3,w0,acc[3][0]); acc[3][1] = fmaf(a3,w1,acc[3][1]);
        acc[3][2] = fmaf(a3,w2,acc[3][2]); acc[3][3] = fmaf(a3,w3,acc[3][3]);
    }
    int obase = nt * 64 + ty * 4;
    if (nt < 3){
        #pragma unroll
        for (int j = 0; j < 4; ++j){
            float4 v = make_float4(acc[0][j], acc[1][j], acc[2][j], acc[3][j]);
            *(float4*)&xin[((size_t)b * DI + obase + j) * L_ + posbase + tx * 4] = v;
        }
    } else {
        #pragma unroll
        for (int i = 0; i < 4; ++i){
            float4 v = make_float4(acc[i][0], acc[i][1], acc[i][2], acc[i][3]);
            *(float4*)&z[((size_t)b * L_ + posbase + tx * 4 + i) * DI + (obase - 192)] = v;
        }
    }
}

// ---------------- K2: depthwise 3x3 conv + bias + SiLU; writes xc (hw) and xcT (wh)
__global__ __launch_bounds__(256) void k_conv(const float* __restrict__ xin,
        const float* __restrict__ cw, const float* __restrict__ cb,
        float* __restrict__ xc, float* __restrict__ xcT){
    int id = blockIdx.x;                   // B*DI*4
    int t = id & 3; int c = (id >> 2) % DI; int b = id / (4 * DI);
    int h0 = (t >> 1) * 32, w0 = (t & 1) * 32;
    __shared__ float in_s[34][36];
    __shared__ float out_s[32][33];
    const float* src = xin + ((size_t)b * DI + c) * L_;
    for (int i = threadIdx.x; i < 34 * 34; i += 256){
        int r = i / 34, q = i % 34;
        int hh = h0 + r - 1, ww = w0 + q - 1;
        float v = 0.f;
        if (hh >= 0 && hh < H_ && ww >= 0 && ww < W_) v = src[hh * W_ + ww];
        in_s[r][q] = v;
    }
    __syncthreads();
    float w9[9];
    #pragma unroll
    for (int j = 0; j < 9; ++j) w9[j] = cw[c * 9 + j];
    float bias = cb[c];
    for (int i = threadIdx.x; i < 32 * 32; i += 256){
        int r = i >> 5, q = i & 31;
        float acc = bias;
        #pragma unroll
        for (int dy = 0; dy < 3; ++dy)
            #pragma unroll
            for (int dx = 0; dx < 3; ++dx)
                acc = fmaf(w9[dy * 3 + dx], in_s[r + dy][q + dx], acc);
        acc = siluf(acc);
        out_s[r][q] = acc;
        xc[((size_t)b * DI + c) * L_ + (h0 + r) * W_ + (w0 + q)] = acc;
    }
    __syncthreads();
    for (int i = threadIdx.x; i < 32 * 32; i += 256){
        int r = i >> 5, q = i & 31;  // r = local w, q = local h
        xcT[((size_t)b * DI + c) * L_ + (w0 + r) * H_ + (h0 + q)] = out_s[q][r];
    }
}

// ---------------- K3: x_dbl[b,k,j,l] = sum_c xs[b,k,c,l] * x_proj_w[k,c,j]
// block: 256 threads = 128 l-positions x 2 c-halves; grid B*K*(L/128) = 256
__global__ __launch_bounds__(256) void k_xdbl(const float* __restrict__ xc,
        const float* __restrict__ xcT, const float* __restrict__ xpw,
        float* __restrict__ xdbl){
    int id = blockIdx.x;
    int lt = id & 31; int k = (id >> 5) & 3; int b = id >> 7;
    int lbase = lt * 128;
    __shared__ float ws[DI][NCOEF];        // 29.2 KB
    __shared__ float red[128][NCOEF + 1];  // 20 KB
    for (int i = threadIdx.x; i < DI * NCOEF; i += 256)
        ws[i / NCOEF][i % NCOEF] = xpw[k * DI * NCOEF + i];
    __syncthreads();
    const float* src = ((k & 1) ? xcT : xc) + (size_t)b * DI * L_;
    bool rev = (k >= 2);
    int tx = threadIdx.x & 127;
    int half = threadIdx.x >> 7;
    int l = lbase + tx;
    int lk = rev ? (L_ - 1 - l) : l;
    int ch0 = half * 96;
    float acc[NCOEF];
    #pragma unroll
    for (int j = 0; j < NCOEF; ++j) acc[j] = 0.f;
    for (int c = ch0; c < ch0 + 96; ++c){
        float v = src[(size_t)c * L_ + lk];
        #pragma unroll
        for (int j = 0; j < NCOEF; ++j) acc[j] = fmaf(v, ws[c][j], acc[j]);
    }
    if (half == 1){
        #pragma unroll
        for (int j = 0; j < NCOEF; ++j) red[tx][j] = acc[j];
    }
    __syncthreads();
    if (half == 0){
        float* dst = xdbl + (size_t)(b * KD + k) * NCOEF * L_ + l;
        #pragma unroll
        for (int j = 0; j < NCOEF; ++j) dst[(size_t)j * L_] = acc[j] + red[tx][j];
    }
}

// ---------------- K4: scan phase 1 — per-chunk summaries P (prod dA) and Q
__global__ __launch_bounds__(192) void k_scan1(const float* __restrict__ xc,
        const float* __restrict__ xcT, const float* __restrict__ xdbl,
        const float* __restrict__ dtw, const float* __restrict__ dtb,
        const float* __restrict__ Alog,
        float* __restrict__ Pbuf, float* __restrict__ Qbuf){
    int id = blockIdx.x;                   // B*K*NCH = 1024
    int ch = id & (NCH - 1); int k = (id >> 7) & 3; int b = id >> 9;
    int lbase = ch * CHUNK;
    __shared__ float u_s[DI][CHUNK + 1];
    __shared__ float co_s[DTR + NST][CHUNK];
    const float* src = ((k & 1) ? xcT : xc) + (size_t)b * DI * L_;
    bool rev = (k >= 2);
    for (int i = threadIdx.x; i < DI * CHUNK; i += 192){
        int r = i >> 5, q = i & 31;
        int lk = rev ? (L_ - 1 - (lbase + q)) : (lbase + q);
        u_s[r][q] = src[(size_t)r * L_ + lk];
    }
    const float* xd = xdbl + (size_t)(b * KD + k) * NCOEF * L_ + lbase;
    for (int i = threadIdx.x; i < (DTR + NST) * CHUNK; i += 192){
        int r = i >> 5, q = i & 31;
        co_s[r][q] = xd[(size_t)r * L_ + q];
    }
    __syncthreads();
    int d = threadIdx.x;
    int kd = k * DI + d;
    float wdt[DTR];
    #pragma unroll
    for (int r = 0; r < DTR; ++r) wdt[r] = dtw[kd * DTR + r];
    float bias = dtb[kd];
    float A[NST];
    #pragma unroll
    for (int n = 0; n < NST; ++n) A[n] = -__expf(Alog[kd * NST + n]);
    float P[NST], Q[NST];
    #pragma unroll
    for (int n = 0; n < NST; ++n){ P[n] = 1.f; Q[n] = 0.f; }
    for (int i = 0; i < CHUNK; ++i){
        float draw = bias;
        #pragma unroll
        for (int r = 0; r < DTR; ++r) draw = fmaf(wdt[r], co_s[r][i], draw);
        float delta = softplusf(draw);
        float du = delta * u_s[d][i];
        #pragma unroll
        for (int n = 0; n < NST; ++n){
            float dA = __expf(delta * A[n]);
            P[n] *= dA;
            Q[n] = fmaf(dA, Q[n], du * co_s[DTR + n][i]);
        }
    }
    size_t base = ((size_t)((b * KD + k) * NCH + ch) * NST) * DI + d;
    #pragma unroll
    for (int n = 0; n < NST; ++n){
        Pbuf[base + (size_t)n * DI] = P[n];
        Qbuf[base + (size_t)n * DI] = Q[n];
    }
}

// ---------------- K5: scan phase 2 — inter-chunk scan; Qbuf becomes x_start per chunk
__global__ __launch_bounds__(256) void k_scan2(const float* __restrict__ Pbuf,
        float* __restrict__ Qbuf){
    int t = blockIdx.x * 256 + threadIdx.x;   // B*K*NST*DI = 24576
    if (t >= B_ * KD * NST * DI) return;
    int d = t % DI; int n = (t / DI) % NST; int bk = t / (DI * NST);
    size_t stride = (size_t)NST * DI;
    size_t idx = (size_t)bk * NCH * stride + (size_t)n * DI + d;
    float x = 0.f;
    #pragma unroll 4
    for (int c = 0; c < NCH; ++c){
        float p = Pbuf[idx];
        float q = Qbuf[idx];
        Qbuf[idx] = x;                 // x_start for this chunk
        x = fmaf(p, x, q);
        idx += stride;
    }
}

// ---------------- K6: scan phase 3 — replay with x_start, emit y (plain stores, [l][d] layout)
__global__ __launch_bounds__(192) void k_scan3(const float* __restrict__ xc,
        const float* __restrict__ xcT, const float* __restrict__ xdbl,
        const float* __restrict__ dtw, const float* __restrict__ dtb,
        const float* __restrict__ Alog, const float* __restrict__ Dskip,
        const float* __restrict__ Qbuf,
        float* __restrict__ y0, float* __restrict__ y1,
        float* __restrict__ y2, float* __restrict__ y3){
    int id = blockIdx.x;                   // 1024
    int ch = id & (NCH - 1); int k = (id >> 7) & 3; int b = id >> 9;
    int lbase = ch * CHUNK;
    __shared__ float u_s[DI][CHUNK + 1];
    __shared__ float co_s[NCOEF][CHUNK];
    __shared__ float y_s[DI][9];
    const float* src = ((k & 1) ? xcT : xc) + (size_t)b * DI * L_;
    bool rev = (k >= 2);
    for (int i = threadIdx.x; i < DI * CHUNK; i += 192){
        int r = i >> 5, q = i & 31;
        int lk = rev ? (L_ - 1 - (lbase + q)) : (lbase + q);
        u_s[r][q] = src[(size_t)r * L_ + lk];
    }
    const float* xd = xdbl + (size_t)(b * KD + k) * NCOEF * L_ + lbase;
    for (int i = threadIdx.x; i < NCOEF * CHUNK; i += 192){
        int r = i >> 5, q = i & 31;
        co_s[r][q] = xd[(size_t)r * L_ + q];
    }
    __syncthreads();
    int d = threadIdx.x;
    int kd = k * DI + d;
    float wdt[DTR];
    #pragma unroll
    for (int r = 0; r < DTR; ++r) wdt[r] = dtw[kd * DTR + r];
    float bias = dtb[kd];
    float A[NST];
    #pragma unroll
    for (int n = 0; n < NST; ++n) A[n] = -__expf(Alog[kd * NST + n]);
    float Dval = Dskip[kd];
    size_t base = ((size_t)((b * KD + k) * NCH + ch) * NST) * DI + d;
    float xst[NST];
    #pragma unroll
    for (int n = 0; n < NST; ++n) xst[n] = Qbuf[base + (size_t)n * DI];
    float* dst = (k == 0 ? y0 : k == 1 ? y1 : k == 2 ? y2 : y3) + (size_t)b * L_ * DI;
    for (int blk = 0; blk < CHUNK / 8; ++blk){
        #pragma unroll
        for (int ii = 0; ii < 8; ++ii){
            int i = blk * 8 + ii;
            float draw = bias;
            #pragma unroll
            for (int r = 0; r < DTR; ++r) draw = fmaf(wdt[r], co_s[r][i], draw);
            float delta = softplusf(draw);
            float du = delta * u_s[d][i];
            float yp0 = 0.f, yp1 = 0.f, yp2 = 0.f, yp3 = 0.f;
            #pragma unroll
            for (int n = 0; n < NST; n += 4){
                float dA0 = __expf(delta * A[n+0]);
                float dA1 = __expf(delta * A[n+1]);
                float dA2 = __expf(delta * A[n+2]);
                float dA3 = __expf(delta * A[n+3]);
                xst[n+0] = fmaf(dA0, xst[n+0], du * co_s[DTR + n+0][i]);
                xst[n+1] = fmaf(dA1, xst[n+1], du * co_s[DTR + n+1][i]);
                xst[n+2] = fmaf(dA2, xst[n+2], du * co_s[DTR + n+2][i]);
                xst[n+3] = fmaf(dA3, xst[n+3], du * co_s[DTR + n+3][i]);
                yp0 = fmaf(xst[n+0], co_s[DTR + NST + n+0][i], yp0);
                yp1 = fmaf(xst[n+1], co_s[DTR + NST + n+1][i], yp1);
                yp2 = fmaf(xst[n+2], co_s[DTR + NST + n+2][i], yp2);
                yp3 = fmaf(xst[n+3], co_s[DTR + NST + n+3][i], yp3);
            }
            y_s[d][ii] = fmaf(u_s[d][i], Dval, (yp0 + yp1) + (yp2 + yp3));
        }
        __syncthreads();
        for (int j = threadIdx.x; j < DI * 8; j += 192){
            int q = j / DI, r = j % DI;
            int i = blk * 8 + q;
            int lk = rev ? (L_ - 1 - (lbase + i)) : (lbase + i);
            dst[(size_t)lk * DI + r] = y_s[r][q];
        }
        __syncthreads();
    }
}

// ---------------- K7: merge 4 directions + LayerNorm + SiLU(z) gate -> yg[b,l,d]
__global__ __launch_bounds__(256) void k_ln(const float* __restrict__ y0,
        const float* __restrict__ y1, const float* __restrict__ y2,
        const float* __restrict__ y3, const float* __restrict__ z,
        const float* __restrict__ lnw, const float* __restrict__ lnb,
        float* __restrict__ yg){
    int pos = blockIdx.x * 4 + (threadIdx.x >> 6);   // 0 .. B*L-1
    int b = pos >> 12; int l = pos & (L_ - 1);
    int h = l >> 6, w = l & 63;
    int lwh = (w << 6) | h;
    int lane = threadIdx.x & 63;
    size_t bl  = ((size_t)b * L_ + l)   * DI;
    size_t blw = ((size_t)b * L_ + lwh) * DI;
    float v[3];
    float s = 0.f, sq = 0.f;
    #pragma unroll
    for (int j = 0; j < 3; ++j){
        int d = lane + j * 64;
        float t = (y0[bl + d] + y2[bl + d]) + (y1[blw + d] + y3[blw + d]);
        v[j] = t;
        s += t; sq = fmaf(t, t, sq);
    }
    #pragma unroll
    for (int off = 32; off > 0; off >>= 1){
        s  += __shfl_xor(s, off);
        sq += __shfl_xor(sq, off);
    }
    float mu = s * (1.f / DI);
    float rs = rsqrtf(sq * (1.f / DI) - mu * mu + 1e-5f);
    #pragma unroll
    for (int j = 0; j < 3; ++j){
        int d = lane + j * 64;
        float val = (v[j] - mu) * rs * lnw[d] + lnb[d];
        float zv = z[bl + d];
        yg[bl + d] = val * siluf(zv);
    }
}

// ---------------- K8: out_proj GEMM. out[8192][96] = yg[8192][192] @ W^T. M-tile 32.
#define KC 48
__global__ __launch_bounds__(256) void k_outproj(const float* __restrict__ yg,
        const float* __restrict__ w, float* __restrict__ out){
    __shared__ float ys[32][DI + 1];
    __shared__ float Ws[DM][KC + 1];
    int mt = blockIdx.x;                   // 256
    int b = mt >> 7; int posbase = (mt & 127) << 5;
    const float* src = yg + ((size_t)b * L_ + posbase) * DI;   // 6144 contiguous
    for (int i4 = threadIdx.x; i4 < 1536; i4 += 256){
        int i = i4 * 4;
        float4 va = *(const float4*)(src + i);
        int r = i / DI, c = i % DI;
        ys[r][c] = va.x; ys[r][c+1] = va.y; ys[r][c+2] = va.z; ys[r][c+3] = va.w;
    }
    int tx = threadIdx.x & 7;              // position group (4)
    int ty = threadIdx.x >> 3;             // output group (3)
    float acc[4][3];
    #pragma unroll
    for (int i = 0; i < 4; ++i)
        #pragma unroll
        for (int j = 0; j < 3; ++j) acc[i][j] = 0.f;
    for (int kc = 0; kc < DI / KC; ++kc){
        __syncthreads();
        for (int i4 = threadIdx.x; i4 < DM * KC / 4; i4 += 256){
            int i = i4 * 4;
            int r = i / KC, c = i % KC;
            float4 vw = *(const float4*)(w + (size_t)r * DI + kc * KC + c);
            Ws[r][c] = vw.x; Ws[r][c+1] = vw.y; Ws[r][c+2] = vw.z; Ws[r][c+3] = vw.w;
        }
        __syncthreads();
        #pragma unroll 4
        for (int kk = 0; kk < KC; ++kk){
            int k = kc * KC + kk;
            float a0 = ys[tx*4+0][k], a1 = ys[tx*4+1][k], a2 = ys[tx*4+2][k], a3 = ys[tx*4+3][k];
            float w0 = Ws[ty*3+0][kk], w1 = Ws[ty*3+1][kk], w2 = Ws[ty*3+2][kk];
            acc[0][0] = fmaf(a0,w0,acc[0][0]); acc[0][1] = fmaf(a0,w1,acc[0][1]); acc[0][2] = fmaf(a0,w2,acc[0][2]);
            acc[1][0] = fmaf(a1,w0,acc[1][0]); acc[1][1] = fmaf(a1,w1,acc[1][1]); acc[1][2] = fmaf(a1,w2,acc[1][2]);
            acc[2][0] = fmaf(a2,w0,acc[2][0]); acc[2][1] = fmaf(a2,w1,acc[2][1]); acc[2][2] = fmaf(a2,w2,acc[2][2]);
            acc[3][0] = fmaf(a3,w0,acc[3][0]); acc[3][1] = fmaf(a3,w1,acc[3][1]); acc[3][2] = fmaf(a3,w2,acc[3][2]);
        }
    }
    #pragma unroll
    for (int i = 0; i < 4; ++i)
        #pragma unroll
        for (int j = 0; j < 3; ++j)
            out[((size_t)b * L_ + posbase + tx * 4 + i) * DM + ty * 3 + j] = acc[i][j];
}

extern "C" void kernel_launch(void* const* d_in, const int* in_sizes, int n_in,
                              void* d_out, int out_size, void* d_ws, size_t ws_size,
                              hipStream_t stream) {
    const float* x    = (const float*)d_in[0];
    const float* ipw  = (const float*)d_in[1];
    const float* cw   = (const float*)d_in[2];
    const float* cb   = (const float*)d_in[3];
    const float* xpw  = (const float*)d_in[4];
    const float* dtw  = (const float*)d_in[5];
    const float* dtb  = (const float*)d_in[6];
    const float* Alog = (const float*)d_in[7];
    const float* Dsk  = (const float*)d_in[8];
    const float* lnw  = (const float*)d_in[9];
    const float* lnb  = (const float*)d_in[10];
    const float* opw  = (const float*)d_in[11];
    float* out = (float*)d_out;

    float* ws = (float*)d_ws;
    const size_t SZ = (size_t)B_ * DI * L_;   // 1,572,864 floats
    float* xin  = ws;                          // slot 0, dead after conv -> y0
    float* xc   = ws + 1 * SZ;                 // slot 1, dead after scan3 -> yg
    float* xcT  = ws + 2 * SZ;                 // slot 2
    float* z    = ws + 3 * SZ;                 // slot 3
    float* xdbl = ws + 4 * SZ;                 // slot 4 (1.25M used)
    float* P    = ws + 5 * SZ;                 // slots 5-6 (2 SZ), dead after scan2 -> y2,y3
    float* Q    = ws + 7 * SZ;                 // slots 7-8 (2 SZ)
    float* y1b  = ws + 9 * SZ;                 // slot 9
    float* y0b  = xin;
    float* y2b  = P;
    float* y3b  = P + SZ;
    float* yg   = xc;

    k_inproj<<<128 * 6, 256, 0, stream>>>(x, ipw, xin, z);
    k_conv<<<B_ * DI * 4, 256, 0, stream>>>(xin, cw, cb, xc, xcT);
    k_xdbl<<<B_ * KD * (L_ / 128), 256, 0, stream>>>(xc, xcT, xpw, xdbl);
    k_scan1<<<B_ * KD * NCH, 192, 0, stream>>>(xc, xcT, xdbl, dtw, dtb, Alog, P, Q);
    k_scan2<<<(B_ * KD * NST * DI + 255) / 256, 256, 0, stream>>>(P, Q);
    k_scan3<<<B_ * KD * NCH, 192, 0, stream>>>(xc, xcT, xdbl, dtw, dtb, Alog, Dsk, Q,
                                               y0b, y1b, y2b, y3b);
    k_ln<<<B_ * L_ / 4, 256, 0, stream>>>(y0b, y1b, y2b, y3b, z, lnw, lnb, yg);
    k_outproj<<<B_ * (L_ / 32), 256, 0, stream>>>(yg, opw, out);
}